// Round 8
// baseline (199.832 us; speedup 1.0000x reference)
//
#include <hip/hip_runtime.h>

#define TPB 256

using half8  = __attribute__((ext_vector_type(8))) _Float16;
using fp16x2 = __attribute__((ext_vector_type(2))) __fp16;
using f32x4  = __attribute__((ext_vector_type(4))) float;

static __device__ __forceinline__ unsigned short h2u(_Float16 h) {
    union { _Float16 h; unsigned short u; } v; v.h = h; return v.u;
}
static __device__ __forceinline__ unsigned pkrtz(float a, float b) {
    fp16x2 h = __builtin_amdgcn_cvt_pkrtz(a, b);
    return __builtin_bit_cast(unsigned, h);
}
template <int CTRL>
static __device__ __forceinline__ float dppmov(float x) {
    return __int_as_float(__builtin_amdgcn_mov_dpp(__float_as_int(x), CTRL, 0xF, 0xF, true));
}
#define DPP_SWAP 0xB1   // quad_perm [1,0,3,2]

// ---------- kernel 1 (fused): pack fp16 features + decoupled-lookback scan + rpt fill
//            + (block 0) weight/bias fragment build ----------
// state[b]: (status<<32)|value. status 0=invalid, 1=aggregate, 2=inclusive prefix.
__global__ __launch_bounds__(TPB) void k_prep_fused(const float* __restrict__ x,
                                                    const float* __restrict__ h_dag,
                                                    const float* __restrict__ h_glob,
                                                    const int* __restrict__ ptr,
                                                    const int* __restrict__ job_indices,
                                                    const int* __restrict__ num_exec_acts,
                                                    const float* __restrict__ W1,
                                                    const float* __restrict__ b1,
                                                    const float* __restrict__ W2,
                                                    const float* __restrict__ b2,
                                                    const float* __restrict__ W3,
                                                    const float* __restrict__ b3,
                                                    const float* __restrict__ W4,
                                                    int J,
                                                    unsigned int* __restrict__ feat,
                                                    unsigned long long* __restrict__ state,
                                                    int* __restrict__ rpt,
                                                    uint4* __restrict__ wfrag,
                                                    float4* __restrict__ bfrag)
{
    __shared__ int sc[TPB];
    __shared__ int sPrefix;
    const int tid = threadIdx.x;
    const int b   = blockIdx.x;
    int j = b * TPB + tid;
    int v = 0;
    if (j < J) {
        int ji   = job_indices[j];
        v        = num_exec_acts[ji];
        int node = ptr[ji];
        float f[40];
        f[0] = x[node * 5 + 0];
        f[1] = x[node * 5 + 1];
        f[2] = x[node * 5 + 2];
#pragma unroll
        for (int c = 0; c < 16; c++) f[3 + c]  = h_dag[ji * 16 + c];
#pragma unroll
        for (int c = 0; c < 16; c++) f[19 + c] = h_glob[j * 16 + c];
#pragma unroll
        for (int c = 35; c < 40; c++) f[c] = 0.0f;
        unsigned int w[20];
#pragma unroll
        for (int k = 0; k < 20; k++)
            w[k] = (unsigned)h2u((_Float16)f[2 * k]) | ((unsigned)h2u((_Float16)f[2 * k + 1]) << 16);
        uint4* dst = (uint4*)(feat + (size_t)j * 20);
#pragma unroll
        for (int qq = 0; qq < 5; qq++)
            dst[qq] = make_uint4(w[4 * qq], w[4 * qq + 1], w[4 * qq + 2], w[4 * qq + 3]);
    }
    // block-local inclusive scan of v
    sc[tid] = v;
    __syncthreads();
    for (int d = 1; d < TPB; d <<= 1) {
        int add = (tid >= d) ? sc[tid - d] : 0;
        __syncthreads();
        sc[tid] += add;
        __syncthreads();
    }
    // decoupled lookback (thread TPB-1)
    if (tid == TPB - 1) {
        int total = sc[TPB - 1];
        long long pfx = 0;
        if (b == 0) {
            __threadfence();
            atomicExch(state + 0, (2ULL << 32) | (unsigned)total);
        } else {
            __threadfence();
            atomicExch(state + b, (1ULL << 32) | (unsigned)total);
            int pb = b - 1;
            while (pb >= 0) {
                unsigned long long s = atomicAdd(state + pb, 0ULL);
                unsigned stt = (unsigned)(s >> 32);
                if (stt == 0) { __builtin_amdgcn_s_sleep(1); continue; }
                pfx += (unsigned)(s & 0xffffffffu);
                if (stt == 2) break;
                pb--;
            }
            __threadfence();
            atomicExch(state + b, (2ULL << 32) | (unsigned)((int)pfx + total));
        }
        sPrefix = (int)pfx;
    }
    __syncthreads();
    // rpt fill
    int start = sPrefix + sc[tid] - v;
    if (j < J) {
        for (int k = 0; k < v; k++) rpt[start + k] = j;
    }
    // block 0: weight/bias fragments (lane order = main-kernel register order)
    if (b == 0) {
        int lane = tid & 63;
        int wvv  = tid >> 6;
        int nn = lane & 15, qq = lane >> 4;
        for (int f = wvv; f < 20; f += 4) {
            half8 w;
            if (f < 8) {
                int nt = f >> 1, s = f & 1;
#pragma unroll
                for (int jj = 0; jj < 8; jj++) {
                    int ks = s * 32 + qq * 8 + jj;
                    w[jj] = (ks < 36) ? (_Float16)W1[ks * 64 + nt * 16 + nn] : (_Float16)0.0f;
                }
            } else if (f < 16) {
                int g = f - 8, nt = g >> 1, s = g & 1;
#pragma unroll
                for (int jj = 0; jj < 8; jj++) {
                    int ks = s * 32 + qq * 8 + jj;
                    w[jj] = (_Float16)W2[ks * 64 + nt * 16 + nn];
                }
            } else {
                int g = f - 16, nt = g >> 1, s = g & 1;
#pragma unroll
                for (int jj = 0; jj < 8; jj++) {
                    int ks = s * 32 + qq * 8 + jj;
                    w[jj] = (_Float16)W3[ks * 32 + nt * 16 + nn];
                }
            }
            wfrag[f * 64 + lane] = __builtin_bit_cast(uint4, w);
        }
        if (wvv == 0) bfrag[0 * 64 + lane] = make_float4(b1[nn], b1[16 + nn], b1[32 + nn], b1[48 + nn]);
        if (wvv == 1) bfrag[1 * 64 + lane] = make_float4(b2[nn], b2[16 + nn], b2[32 + nn], b2[48 + nn]);
        if (wvv == 2) bfrag[2 * 64 + lane] = make_float4(b3[nn], b3[16 + nn], W4[nn], W4[16 + nn]);
    }
}

// ---------- kernel 2: fused MFMA MLP, wave-private SINGLE 4KB slab (16KB LDS/block) ----------
// Granule layout: granule(row,c) = halves A[row][8c..8c+7] at P = row*8 + (c ^ ((row>>1)&7)).
// Single slab is safe: per-mt, all ds_reads are issued before the epilogue's ds_writes and
// same-wave LDS ops execute in order; mt=0 writes rows 0..15 never alias mt=1 reads rows 16..31.
__global__ __launch_bounds__(TPB) void k_mlp_mfma(const unsigned int* __restrict__ feat,
                                                  const int* __restrict__ rpt,
                                                  const int* __restrict__ exec_act_idx,
                                                  const uint4* __restrict__ wfrag,
                                                  const float4* __restrict__ bfrag,
                                                  const float* __restrict__ b4,
                                                  float* __restrict__ out, int T, int numTiles)
{
    __shared__ __align__(16) char smem[4 * 4096];
    const int tid  = threadIdx.x;
    const int lane = tid & 63;
    const int wv   = tid >> 6;
    const int n    = lane & 15;
    const int q    = lane >> 4;
    char* slab = smem + wv * 4096;

    // ---- fragment loads: 23 coalesced 16B loads ----
    half8 bw1[4][2], bw2[4][2], bw3[2][2];
#pragma unroll
    for (int nt = 0; nt < 4; nt++)
#pragma unroll
        for (int s = 0; s < 2; s++) {
            bw1[nt][s] = __builtin_bit_cast(half8, wfrag[(nt * 2 + s) * 64 + lane]);
            bw2[nt][s] = __builtin_bit_cast(half8, wfrag[(8 + nt * 2 + s) * 64 + lane]);
        }
#pragma unroll
    for (int nt = 0; nt < 2; nt++)
#pragma unroll
        for (int s = 0; s < 2; s++)
            bw3[nt][s] = __builtin_bit_cast(half8, wfrag[(16 + nt * 2 + s) * 64 + lane]);

    float4 bf1 = bfrag[0 * 64 + lane];
    float4 bf2 = bfrag[1 * 64 + lane];
    float4 bf3 = bfrag[2 * 64 + lane];
    float bb1[4] = {bf1.x, bf1.y, bf1.z, bf1.w};
    float bb2[4] = {bf2.x, bf2.y, bf2.z, bf2.w};
    float bb3[2] = {bf3.x, bf3.y};
    const float w4a = bf3.z, w4b = bf3.w;
    const float b4v = b4[0];
    const int   swr = (n >> 1) & 7;
    const int   odd = n & 1;

    for (int tile = blockIdx.x; tile < numTiles; tile += gridDim.x) {
        const int rowbase = tile * 128 + wv * 32;

        // ---- A1 fragments straight from global ----
        half8 a1[2][2];
#pragma unroll
        for (int mt = 0; mt < 2; mt++) {
            int  rt    = rowbase + 16 * mt + n;
            bool valid = rt < T;
            int  j     = valid ? rpt[rt] : 0;
            const uint4* fsrc = (const uint4*)(feat + (size_t)j * 20);
            uint4 g0 = fsrc[q];
            a1[mt][0] = __builtin_bit_cast(half8, g0);
            uint4 g1 = make_uint4(0, 0, 0, 0);
            if (q == 0) {
                g1 = fsrc[4];
                float fe = valid ? (float)exec_act_idx[rt] * 0.02f : 0.0f;
                g1.y = (g1.y & 0xffffu) | ((unsigned)h2u((_Float16)fe) << 16);
            }
            a1[mt][1] = __builtin_bit_cast(half8, g1);
        }

        // ---- layer 1 -> slab ----
#pragma unroll
        for (int mt = 0; mt < 2; mt++) {
            f32x4 acc[4];
#pragma unroll
            for (int nt = 0; nt < 4; nt++) { f32x4 c; c[0]=c[1]=c[2]=c[3]=bb1[nt]; acc[nt]=c; }
#pragma unroll
            for (int s = 0; s < 2; s++) {
#pragma unroll
                for (int nt = 0; nt < 4; nt++)
                    acc[nt] = __builtin_amdgcn_mfma_f32_16x16x32_f16(a1[mt][s], bw1[nt][s], acc[nt], 0, 0, 0);
            }
            unsigned* sl = (unsigned*)slab;
#pragma unroll
            for (int nt = 0; nt < 4; nt++) {
                float v0 = fmaxf(acc[nt][0], 0.0f), v1 = fmaxf(acc[nt][1], 0.0f);
                float v2 = fmaxf(acc[nt][2], 0.0f), v3 = fmaxf(acc[nt][3], 0.0f);
                float t0 = dppmov<DPP_SWAP>(v0), t1 = dppmov<DPP_SWAP>(v1);
                float t2 = dppmov<DPP_SWAP>(v2), t3 = dppmov<DPP_SWAP>(v3);
                unsigned u0 = pkrtz(odd ? t2 : v0, odd ? v2 : t0);
                unsigned u1 = pkrtz(odd ? t3 : v1, odd ? v3 : t1);
                int rowA = 16 * mt + 4 * q + (odd ? 2 : 0);
                int c    = 2 * nt + (n >> 3);
                int a0   = (rowA * 8 + (c ^ ((rowA >> 1) & 7))) * 4 + ((n >> 1) & 3);
                sl[a0] = u0; sl[a0 + 32] = u1;
            }
        }

        // ---- layer 2: slab -> slab (reads precede writes per mt; same-wave DS is in-order) ----
#pragma unroll
        for (int mt = 0; mt < 2; mt++) {
            const int M0 = 16 * mt;
            f32x4 acc[4];
#pragma unroll
            for (int nt = 0; nt < 4; nt++) { f32x4 c; c[0]=c[1]=c[2]=c[3]=bb2[nt]; acc[nt]=c; }
            half8 a0r = *(const half8*)(slab + ((M0 + n) * 8 + ((0 * 4 + q) ^ swr)) * 16);
            half8 a1r = *(const half8*)(slab + ((M0 + n) * 8 + ((1 * 4 + q) ^ swr)) * 16);
#pragma unroll
            for (int nt = 0; nt < 4; nt++)
                acc[nt] = __builtin_amdgcn_mfma_f32_16x16x32_f16(a0r, bw2[nt][0], acc[nt], 0, 0, 0);
#pragma unroll
            for (int nt = 0; nt < 4; nt++)
                acc[nt] = __builtin_amdgcn_mfma_f32_16x16x32_f16(a1r, bw2[nt][1], acc[nt], 0, 0, 0);
            unsigned* sl = (unsigned*)slab;
#pragma unroll
            for (int nt = 0; nt < 4; nt++) {
                float v0 = fmaxf(acc[nt][0], 0.0f), v1 = fmaxf(acc[nt][1], 0.0f);
                float v2 = fmaxf(acc[nt][2], 0.0f), v3 = fmaxf(acc[nt][3], 0.0f);
                float t0 = dppmov<DPP_SWAP>(v0), t1 = dppmov<DPP_SWAP>(v1);
                float t2 = dppmov<DPP_SWAP>(v2), t3 = dppmov<DPP_SWAP>(v3);
                unsigned u0 = pkrtz(odd ? t2 : v0, odd ? v2 : t0);
                unsigned u1 = pkrtz(odd ? t3 : v1, odd ? v3 : t1);
                int rowA = M0 + 4 * q + (odd ? 2 : 0);
                int c    = 2 * nt + (n >> 3);
                int a0   = (rowA * 8 + (c ^ ((rowA >> 1) & 7))) * 4 + ((n >> 1) & 3);
                sl[a0] = u0; sl[a0 + 32] = u1;
            }
        }

        // ---- layer 3 + 4: slab -> scores ----
#pragma unroll
        for (int mt = 0; mt < 2; mt++) {
            const int M0 = 16 * mt;
            f32x4 acc[2];
#pragma unroll
            for (int nt = 0; nt < 2; nt++) { f32x4 c; c[0]=c[1]=c[2]=c[3]=bb3[nt]; acc[nt]=c; }
#pragma unroll
            for (int s = 0; s < 2; s++) {
                half8 a = *(const half8*)(slab + ((M0 + n) * 8 + ((s * 4 + q) ^ swr)) * 16);
#pragma unroll
                for (int nt = 0; nt < 2; nt++)
                    acc[nt] = __builtin_amdgcn_mfma_f32_16x16x32_f16(a, bw3[nt][s], acc[nt], 0, 0, 0);
            }
            f32x4 red;
#pragma unroll
            for (int r = 0; r < 4; r++)
                red[r] = fmaxf(acc[0][r], 0.0f) * w4a + fmaxf(acc[1][r], 0.0f) * w4b;
#pragma unroll
            for (int r = 0; r < 4; r++) {
                red[r] += dppmov<0x121>(red[r]);   // row_ror:1
                red[r] += dppmov<0x122>(red[r]);   // row_ror:2
                red[r] += dppmov<0x124>(red[r]);   // row_ror:4
                red[r] += dppmov<0x128>(red[r]);   // row_ror:8
            }
            int t = rowbase + M0 + q * 4 + n;
            float val = (n == 0) ? red[0] : (n == 1) ? red[1] : (n == 2) ? red[2] : red[3];
            if (n < 4 && t < T) out[t] = val + b4v;
        }
    }
}

extern "C" void kernel_launch(void* const* d_in, const int* in_sizes, int n_in,
                              void* d_out, int out_size, void* d_ws, size_t ws_size,
                              hipStream_t stream)
{
    const float* x             = (const float*)d_in[0];
    const float* h_dag         = (const float*)d_in[1];
    const float* h_glob        = (const float*)d_in[2];
    const int*   ptr           = (const int*)d_in[3];
    const int*   job_indices   = (const int*)d_in[4];
    const int*   num_exec_acts = (const int*)d_in[5];
    const int*   exec_act_idx  = (const int*)d_in[6];
    const float* W1 = (const float*)d_in[7];
    const float* b1 = (const float*)d_in[8];
    const float* W2 = (const float*)d_in[9];
    const float* b2 = (const float*)d_in[10];
    const float* W3 = (const float*)d_in[11];
    const float* b3 = (const float*)d_in[12];
    const float* W4 = (const float*)d_in[13];
    const float* b4 = (const float*)d_in[14];
    float* out = (float*)d_out;

    int J  = in_sizes[4];
    int T  = in_sizes[6];
    int nb = (J + TPB - 1) / TPB;

    // workspace layout
    char* wsp = (char*)d_ws;
    int* rpt = (int*)wsp;
    wsp += (((size_t)T * 4) + 255) / 256 * 256;
    unsigned long long* state = (unsigned long long*)wsp;
    wsp += (((size_t)nb * 8) + 255) / 256 * 256;
    uint4* wfrag = (uint4*)wsp;            // 20*64*16 B
    wsp += 20 * 64 * 16;
    float4* bfrag = (float4*)wsp;          // 3*64*16 B
    wsp += 3 * 64 * 16;
    unsigned int* feat = (unsigned int*)wsp;   // J*20 words

    hipMemsetAsync(state, 0, (size_t)nb * 8, stream);
    k_prep_fused<<<nb, TPB, 0, stream>>>(x, h_dag, h_glob, ptr, job_indices, num_exec_acts,
                                         W1, b1, W2, b2, W3, b3, W4,
                                         J, feat, state, rpt, wfrag, bfrag);

    int numTiles = (T + 127) / 128;
    int grid = numTiles < 1024 ? numTiles : 1024;
    k_mlp_mfma<<<grid, TPB, 0, stream>>>(feat, rpt, exec_act_idx, wfrag, bfrag, b4,
                                         out, T, numTiles);
}

// Round 9
// 196.587 us; speedup vs baseline: 1.0165x; 1.0165x over previous
//
#include <hip/hip_runtime.h>

#define TPB 256

using half8  = __attribute__((ext_vector_type(8))) _Float16;
using fp16x2 = __attribute__((ext_vector_type(2))) __fp16;
using f32x4  = __attribute__((ext_vector_type(4))) float;

static __device__ __forceinline__ unsigned short h2u(_Float16 h) {
    union { _Float16 h; unsigned short u; } v; v.h = h; return v.u;
}
static __device__ __forceinline__ unsigned pkrtz(float a, float b) {
    fp16x2 h = __builtin_amdgcn_cvt_pkrtz(a, b);
    return __builtin_bit_cast(unsigned, h);
}
template <int CTRL>
static __device__ __forceinline__ float dppmov(float x) {
    return __int_as_float(__builtin_amdgcn_mov_dpp(__float_as_int(x), CTRL, 0xF, 0xF, true));
}
#define DPP_SWAP 0xB1   // quad_perm [1,0,3,2]

// ---------- kernel 1 (fused): per-job h1_pre = b1 + f[0:35] @ W1 (fp32 -> fp16, A-frag
// granule order) + ticket-based global scan of n_sel + rpt fill + (block 0) W2/W3/w1r/bias frags.
// state[0]=ticket counter, state[1]=done flag, state[2+b]=aggregate then exclusive prefix.
__global__ __launch_bounds__(TPB) void k_prep_fused(const float* __restrict__ x,
                                                    const float* __restrict__ h_dag,
                                                    const float* __restrict__ h_glob,
                                                    const int* __restrict__ ptr,
                                                    const int* __restrict__ job_indices,
                                                    const int* __restrict__ num_exec_acts,
                                                    const float* __restrict__ W1,
                                                    const float* __restrict__ b1,
                                                    const float* __restrict__ W2,
                                                    const float* __restrict__ b2,
                                                    const float* __restrict__ W3,
                                                    const float* __restrict__ b3,
                                                    const float* __restrict__ W4,
                                                    int J, int nb,
                                                    uint4* __restrict__ h1p,
                                                    int* __restrict__ state,
                                                    int* __restrict__ rpt,
                                                    uint4* __restrict__ wfrag,
                                                    float4* __restrict__ bfrag)
{
    __shared__ int sc[TPB];
    __shared__ int sb[TPB];
    __shared__ int sScanner;
    __shared__ int sMyOff;
    const int tid = threadIdx.x;
    const int b   = blockIdx.x;
    int j = b * TPB + tid;
    bool valid = j < J;
    int v = 0;

    if (valid) {
        int ji   = job_indices[j];
        v        = num_exec_acts[ji];
        int node = ptr[ji];
        float f[35];
        f[0] = x[node * 5 + 0];
        f[1] = x[node * 5 + 1];
        f[2] = x[node * 5 + 2];
#pragma unroll
        for (int c = 0; c < 16; c++) f[3 + c]  = h_dag[ji * 16 + c];
#pragma unroll
        for (int c = 0; c < 16; c++) f[19 + c] = h_glob[j * 16 + c];

        float acc[64];
#pragma unroll
        for (int o = 0; o < 64; o++) acc[o] = b1[o];          // uniform -> s_load
#pragma unroll
        for (int i = 0; i < 35; i++) {
            float fi = f[i];
#pragma unroll
            for (int o = 0; o < 64; o++) acc[o] = fmaf(fi, W1[i * 64 + o], acc[o]);
        }
        // store fp16 (RTN via cast), natural half order = A-frag granule order
        uint4* dst = h1p + (size_t)j * 8;
#pragma unroll
        for (int g = 0; g < 8; g++) {
            unsigned w0 = (unsigned)h2u((_Float16)acc[8 * g + 0]) | ((unsigned)h2u((_Float16)acc[8 * g + 1]) << 16);
            unsigned w1 = (unsigned)h2u((_Float16)acc[8 * g + 2]) | ((unsigned)h2u((_Float16)acc[8 * g + 3]) << 16);
            unsigned w2 = (unsigned)h2u((_Float16)acc[8 * g + 4]) | ((unsigned)h2u((_Float16)acc[8 * g + 5]) << 16);
            unsigned w3 = (unsigned)h2u((_Float16)acc[8 * g + 6]) | ((unsigned)h2u((_Float16)acc[8 * g + 7]) << 16);
            dst[g] = make_uint4(w0, w1, w2, w3);
        }
    }

    // block-local inclusive scan of v
    sc[tid] = v;
    __syncthreads();
    for (int d = 1; d < TPB; d <<= 1) {
        int add = (tid >= d) ? sc[tid - d] : 0;
        __syncthreads();
        sc[tid] += add;
        __syncthreads();
    }
    int incl = sc[tid];

    // publish aggregate, take ticket; last block becomes scanner
    if (tid == TPB - 1) {
        atomicExch(&state[2 + b], incl);      // block total (atomic store, bypasses L1)
        __threadfence();
        int t = atomicAdd(&state[0], 1);
        sScanner = (t == nb - 1) ? 1 : 0;
    }
    __syncthreads();

    if (sScanner) {
        int a = (tid < nb) ? atomicAdd(&state[2 + tid], 0) : 0;
        sb[tid] = a;
        __syncthreads();
        for (int d = 1; d < TPB; d <<= 1) {
            int add = (tid >= d) ? sb[tid - d] : 0;
            __syncthreads();
            sb[tid] += add;
            __syncthreads();
        }
        if (tid < nb) atomicExch(&state[2 + tid], sb[tid] - a);   // exclusive prefix
        __threadfence();
        if (tid == 0) atomicExch(&state[1], 1);
    }
    if (tid == 0) {
        while (atomicAdd(&state[1], 0) == 0) __builtin_amdgcn_s_sleep(2);
        sMyOff = atomicAdd(&state[2 + b], 0);
    }
    __syncthreads();

    int start = sMyOff + incl - v;
    if (valid) {
        for (int k = 0; k < v; k++) rpt[start + k] = j;
    }

    // block 0: weight/bias fragments in main-kernel lane order
    if (b == 0) {
        int lane = tid & 63;
        int wvv  = tid >> 6;
        int nn = lane & 15, qq = lane >> 4;
        for (int f = wvv; f < 14; f += 4) {
            half8 w;
            if (f < 8) {            // W2 frags
                int nt = f >> 1, s = f & 1;
#pragma unroll
                for (int jj = 0; jj < 8; jj++) {
                    int ks = s * 32 + qq * 8 + jj;
                    w[jj] = (_Float16)W2[ks * 64 + nt * 16 + nn];
                }
            } else if (f < 12) {    // W3 frags
                int g = f - 8, nt = g >> 1, s = g & 1;
#pragma unroll
                for (int jj = 0; jj < 8; jj++) {
                    int ks = s * 32 + qq * 8 + jj;
                    w[jj] = (_Float16)W3[ks * 32 + nt * 16 + nn];
                }
            } else {                // W1 row 35 (exec) in A-frag k-order
                int s = f - 12;
#pragma unroll
                for (int jj = 0; jj < 8; jj++)
                    w[jj] = (_Float16)W1[35 * 64 + s * 32 + qq * 8 + jj];
            }
            wfrag[f * 64 + lane] = __builtin_bit_cast(uint4, w);
        }
        if (wvv == 0) bfrag[lane]      = make_float4(b2[nn], b2[16 + nn], b2[32 + nn], b2[48 + nn]);
        if (wvv == 1) bfrag[64 + lane] = make_float4(b3[nn], b3[16 + nn], W4[nn], W4[16 + nn]);
    }
}

// ---------- kernel 2: fused MFMA MLP; layer 1 folded into registers, single 4KB slab/wave ----------
// Granule layout: granule(row,c) = halves A[row][8c..8c+7] at P = row*8 + (c ^ ((row>>1)&7)).
__global__ __launch_bounds__(TPB) void k_mlp_mfma(const uint4* __restrict__ h1p,
                                                  const int* __restrict__ rpt,
                                                  const int* __restrict__ exec_act_idx,
                                                  const uint4* __restrict__ wfrag,
                                                  const float4* __restrict__ bfrag,
                                                  const float* __restrict__ b4,
                                                  float* __restrict__ out, int T, int numTiles)
{
    __shared__ __align__(16) char smem[4 * 4096];
    const int tid  = threadIdx.x;
    const int lane = tid & 63;
    const int wv   = tid >> 6;
    const int n    = lane & 15;
    const int q    = lane >> 4;
    char* slab = smem + wv * 4096;

    // ---- fragment loads: 14 coalesced 16B + 2 bias loads ----
    half8 bw2[4][2], bw3[2][2], w1r[2];
#pragma unroll
    for (int nt = 0; nt < 4; nt++)
#pragma unroll
        for (int s = 0; s < 2; s++)
            bw2[nt][s] = __builtin_bit_cast(half8, wfrag[(nt * 2 + s) * 64 + lane]);
#pragma unroll
    for (int nt = 0; nt < 2; nt++)
#pragma unroll
        for (int s = 0; s < 2; s++)
            bw3[nt][s] = __builtin_bit_cast(half8, wfrag[(8 + nt * 2 + s) * 64 + lane]);
#pragma unroll
    for (int s = 0; s < 2; s++)
        w1r[s] = __builtin_bit_cast(half8, wfrag[(12 + s) * 64 + lane]);

    float4 bf2 = bfrag[lane];
    float4 bf3 = bfrag[64 + lane];
    float bb2[4] = {bf2.x, bf2.y, bf2.z, bf2.w};
    float bb3[2] = {bf3.x, bf3.y};
    const float w4a = bf3.z, w4b = bf3.w;
    const float b4v = b4[0];
    const int   swr = (n >> 1) & 7;
    const int   odd = n & 1;

    for (int tile = blockIdx.x; tile < numTiles; tile += gridDim.x) {
        const int rowbase = tile * 128 + wv * 32;

        // ---- layer 1 (folded): a2 = relu(h1_pre + exec * w1row35), all in registers ----
        half8 a2[2][2];
#pragma unroll
        for (int mt = 0; mt < 2; mt++) {
            int  rt    = rowbase + 16 * mt + n;
            bool vld   = rt < T;
            int  j     = vld ? rpt[rt] : 0;
            float fe   = vld ? (float)exec_act_idx[rt] * 0.02f : 0.0f;
            _Float16 feh = (_Float16)fe;
            const uint4* hp = h1p + (size_t)j * 8;
#pragma unroll
            for (int s = 0; s < 2; s++) {
                half8 h = __builtin_bit_cast(half8, hp[s * 4 + q]);
                half8 a;
#pragma unroll
                for (int jj = 0; jj < 8; jj++) {
                    _Float16 t = h[jj] + feh * w1r[s][jj];
                    a[jj] = (t > (_Float16)0.0f) ? t : (_Float16)0.0f;
                }
                a2[mt][s] = a;
            }
        }

        // ---- layer 2: registers -> MFMA -> slab (A-layout, swizzled) ----
#pragma unroll
        for (int mt = 0; mt < 2; mt++) {
            f32x4 acc[4];
#pragma unroll
            for (int nt = 0; nt < 4; nt++) { f32x4 c; c[0]=c[1]=c[2]=c[3]=bb2[nt]; acc[nt]=c; }
#pragma unroll
            for (int s = 0; s < 2; s++) {
#pragma unroll
                for (int nt = 0; nt < 4; nt++)
                    acc[nt] = __builtin_amdgcn_mfma_f32_16x16x32_f16(a2[mt][s], bw2[nt][s], acc[nt], 0, 0, 0);
            }
            unsigned* sl = (unsigned*)slab;
#pragma unroll
            for (int nt = 0; nt < 4; nt++) {
                float v0 = fmaxf(acc[nt][0], 0.0f), v1 = fmaxf(acc[nt][1], 0.0f);
                float v2 = fmaxf(acc[nt][2], 0.0f), v3 = fmaxf(acc[nt][3], 0.0f);
                float t0 = dppmov<DPP_SWAP>(v0), t1 = dppmov<DPP_SWAP>(v1);
                float t2 = dppmov<DPP_SWAP>(v2), t3 = dppmov<DPP_SWAP>(v3);
                unsigned u0 = pkrtz(odd ? t2 : v0, odd ? v2 : t0);
                unsigned u1 = pkrtz(odd ? t3 : v1, odd ? v3 : t1);
                int rowA = 16 * mt + 4 * q + (odd ? 2 : 0);
                int c    = 2 * nt + (n >> 3);
                int a0   = (rowA * 8 + (c ^ ((rowA >> 1) & 7))) * 4 + ((n >> 1) & 3);
                sl[a0] = u0; sl[a0 + 32] = u1;
            }
        }

        // ---- layer 3 + 4: slab -> scores (DPP row_ror reduce) ----
#pragma unroll
        for (int mt = 0; mt < 2; mt++) {
            const int M0 = 16 * mt;
            f32x4 acc[2];
#pragma unroll
            for (int nt = 0; nt < 2; nt++) { f32x4 c; c[0]=c[1]=c[2]=c[3]=bb3[nt]; acc[nt]=c; }
#pragma unroll
            for (int s = 0; s < 2; s++) {
                half8 a = *(const half8*)(slab + ((M0 + n) * 8 + ((s * 4 + q) ^ swr)) * 16);
#pragma unroll
                for (int nt = 0; nt < 2; nt++)
                    acc[nt] = __builtin_amdgcn_mfma_f32_16x16x32_f16(a, bw3[nt][s], acc[nt], 0, 0, 0);
            }
            f32x4 red;
#pragma unroll
            for (int r = 0; r < 4; r++)
                red[r] = fmaxf(acc[0][r], 0.0f) * w4a + fmaxf(acc[1][r], 0.0f) * w4b;
#pragma unroll
            for (int r = 0; r < 4; r++) {
                red[r] += dppmov<0x121>(red[r]);   // row_ror:1
                red[r] += dppmov<0x122>(red[r]);   // row_ror:2
                red[r] += dppmov<0x124>(red[r]);   // row_ror:4
                red[r] += dppmov<0x128>(red[r]);   // row_ror:8
            }
            int t = rowbase + M0 + q * 4 + n;
            float val = (n == 0) ? red[0] : (n == 1) ? red[1] : (n == 2) ? red[2] : red[3];
            if (n < 4 && t < T) out[t] = val + b4v;
        }
    }
}

extern "C" void kernel_launch(void* const* d_in, const int* in_sizes, int n_in,
                              void* d_out, int out_size, void* d_ws, size_t ws_size,
                              hipStream_t stream)
{
    const float* x             = (const float*)d_in[0];
    const float* h_dag         = (const float*)d_in[1];
    const float* h_glob        = (const float*)d_in[2];
    const int*   ptr           = (const int*)d_in[3];
    const int*   job_indices   = (const int*)d_in[4];
    const int*   num_exec_acts = (const int*)d_in[5];
    const int*   exec_act_idx  = (const int*)d_in[6];
    const float* W1 = (const float*)d_in[7];
    const float* b1 = (const float*)d_in[8];
    const float* W2 = (const float*)d_in[9];
    const float* b2 = (const float*)d_in[10];
    const float* W3 = (const float*)d_in[11];
    const float* b3 = (const float*)d_in[12];
    const float* W4 = (const float*)d_in[13];
    const float* b4 = (const float*)d_in[14];
    float* out = (float*)d_out;

    int J  = in_sizes[4];
    int T  = in_sizes[6];
    int nb = (J + TPB - 1) / TPB;

    // workspace layout
    char* wsp = (char*)d_ws;
    int* rpt = (int*)wsp;
    wsp += (((size_t)T * 4) + 255) / 256 * 256;
    int* state = (int*)wsp;                       // [0]=ticket, [1]=flag, [2..2+nb)
    wsp += (((size_t)(2 + nb) * 4) + 255) / 256 * 256;
    uint4* wfrag = (uint4*)wsp;                   // 14*64*16 B
    wsp += 16 * 64 * 16;
    float4* bfrag = (float4*)wsp;                 // 2*64*16 B
    wsp += 2 * 64 * 16;
    uint4* h1p = (uint4*)wsp;                     // J*8 uint4 = J*128 B

    hipMemsetAsync(state, 0, (size_t)(2 + nb) * 4, stream);
    k_prep_fused<<<nb, TPB, 0, stream>>>(x, h_dag, h_glob, ptr, job_indices, num_exec_acts,
                                         W1, b1, W2, b2, W3, b3, W4,
                                         J, nb, h1p, state, rpt, wfrag, bfrag);

    int numTiles = (T + 127) / 128;
    int grid = numTiles < 1024 ? numTiles : 1024;
    k_mlp_mfma<<<grid, TPB, 0, stream>>>(h1p, rpt, exec_act_idx, wfrag, bfrag, b4,
                                         out, T, numTiles);
}